// Round 9
// baseline (21560.358 us; speedup 1.0000x reference)
//
#include <hip/hip_runtime.h>
#include <hip/hip_bf16.h>

// VRAE forward on gfx950. FP32 I/O; MFMA via bf16 hi/lo planes (~fp32 accuracy).
// R9 = R8 with the mod-5 ring race fixed. R8's sweep ran at phase p==2 and wrote
// ring slots (t4+4..t4+7)%5 — but t4+7 = t4+2 (mod 5), i.e. it overwrote the slot
// being READ by gh-waves in the same phase (no barrier between) -> absmax 0.309.
// Fix: sweep at p==3. Write set {t4+4,t4,t4+1,t4+2}%5 excludes the p==3 reader
// slot (t4+3)%5; slots t4..t4+2 were read in earlier (barrier-separated) phases.

typedef __bf16 bf16;
typedef __bf16 bf16x8 __attribute__((ext_vector_type(8)));
typedef float f32x4 __attribute__((ext_vector_type(4)));

#define MFMA(a,b,c) __builtin_amdgcn_mfma_f32_16x16x32_bf16((a),(b),(c),0,0,0)
#define Z4 (f32x4){0.f,0.f,0.f,0.f}

__device__ __forceinline__ float sigm_(float x){ return 1.f/(1.f+__expf(-x)); }
__device__ __forceinline__ float tanh_(float x){
  x = fminf(15.f, fmaxf(-15.f, x));
  float e = __expf(2.f*x);
  return (e-1.f)/(e+1.f);
}
__device__ __forceinline__ float fin_(float v){ return (v - v == 0.0f) ? v : 0.0f; }
__device__ __forceinline__ void pin_(bf16x8 &v){ asm volatile("" : "+v"(v)); }

// ---------------------------------------------------------------------------
// Weight prep: fp32 -> bf16 hi/lo planes in ws.
// ---------------------------------------------------------------------------
struct PrepJobs {
  const float* src[9];
  bf16* hi[9];
  bf16* lo[9];
  int n[9];
};

__global__ void prep_w(PrepJobs J){
  const int stride = gridDim.x*blockDim.x;
  const int t0 = blockIdx.x*blockDim.x + threadIdx.x;
  for (int j=0;j<9;++j){
    const float* __restrict__ s = J.src[j];
    bf16* __restrict__ h = J.hi[j];
    bf16* __restrict__ l = J.lo[j];
    const int n = J.n[j];
    for (int i=t0;i<n;i+=stride){
      float v = fin_(s[i]);
      bf16 hh = (bf16)v;
      h[i] = hh;
      l[i] = (bf16)(v - (float)hh);
    }
  }
}

// ---------------------------------------------------------------------------
// Encoder. grid=32: blockIdx>>4 = dir, blockIdx&15 = batch slice of 16.
// block=768 (12 waves): waves 0-7 gh+gates (triplet w, resident Whh);
// waves 8-11 gi engine (2 triplets each, 4-step sweeps -> mod-5 ring).
// ---------------------------------------------------------------------------
template<int KIN, bool F32IN>
__global__ __launch_bounds__(768) __attribute__((amdgpu_waves_per_eu(3,3)))
void enc_rec(const void* __restrict__ seqIn_,  // [256,512,KIN] fp32|bf16
             bf16* __restrict__ seqOut,        // [256,512,256] or null
             const bf16* __restrict__ WihHi_, const bf16* __restrict__ WihLo_, // [2,384,KIN]
             const bf16* __restrict__ WhhHi_, const bf16* __restrict__ WhhLo_, // [2,384,128]
             const float* __restrict__ bih_, const float* __restrict__ bhh_,   // [2,384]
             const int* __restrict__ lengths,
             float* __restrict__ hFo, float* __restrict__ hBo)                 // [256,128] or null
{
  constexpr int NKS  = KIN/32;
  constexpr int XSTR = F32IN ? 40 : 264;     // LDS x-row stride (elems)
  constexpr int XPL  = 16*XSTR;
  constexpr int XSLOT= (F32IN?2:1)*XPL;      // per-slot (hi[,lo])
  const int tid  = threadIdx.x;
  const int wave = tid>>6;
  const int lh   = tid&15;
  const int quad = (tid>>4)&3;
  const int dir  = blockIdx.x>>4;
  const int b0   = (blockIdx.x&15)*16;
  const bool ghR = (tid < 512);

  const bf16* __restrict__ WihHi = WihHi_ + (size_t)dir*384*KIN;
  const bf16* __restrict__ WihLo = WihLo_ + (size_t)dir*384*KIN;
  const bf16* __restrict__ WhhHi = WhhHi_ + (size_t)dir*384*128;
  const bf16* __restrict__ WhhLo = WhhLo_ + (size_t)dir*384*128;
  const float* __restrict__ bih = bih_ + dir*384;
  const float* __restrict__ bhh = bhh_ + dir*384;

  __shared__ float ring[5*16*384];           // gi preacts, slot = step%5 (123KB)
  __shared__ bf16 hHi[16*136], hLo[16*136];
  __shared__ bf16 xb[3*XSLOT];               // x staging slots 0..2 (slot3 from global)

  const int Tmax = lengths[b0];              // sorted desc -> slice max
  const int TT   = (Tmax+3)&~3;
  const int lenA = lengths[b0+lh];

  for (int i=tid;i<16*136;i+=768){ hHi[i]=(bf16)0.f; hLo[i]=(bf16)0.f; }

  // ---- gh-wave state (waves 0..7) ----
  const int jc = wave*16 + lh;
  const int cR = jc, cZ = 128+jc, cN = 256+jc;
  bf16x8 wRH[4],wRL[4],wZH[4],wZL[4],wNH[4],wNL[4];
  float bR=0.f,bZ=0.f,bNi=0.f,bNh=0.f;
  int lenRow[4]={0,0,0,0};
  if (ghR){
#pragma unroll
    for (int ks=0;ks<4;++ks){
      const int o = ks*32 + quad*8;
      wRH[ks]=*(const bf16x8*)(WhhHi+(size_t)cR*128+o); wRL[ks]=*(const bf16x8*)(WhhLo+(size_t)cR*128+o);
      wZH[ks]=*(const bf16x8*)(WhhHi+(size_t)cZ*128+o); wZL[ks]=*(const bf16x8*)(WhhLo+(size_t)cZ*128+o);
      wNH[ks]=*(const bf16x8*)(WhhHi+(size_t)cN*128+o); wNL[ks]=*(const bf16x8*)(WhhLo+(size_t)cN*128+o);
      pin_(wRH[ks]); pin_(wRL[ks]); pin_(wZH[ks]); pin_(wZL[ks]); pin_(wNH[ks]); pin_(wNL[ks]);
    }
    bR  = bih[cR]+bhh[cR];
    bZ  = bih[cZ]+bhh[cZ];
    bNi = bih[cN];
    bNh = bhh[cN];
#pragma unroll
    for (int r=0;r<4;++r) lenRow[r] = lengths[b0 + quad*4 + r];
  }

  // ---- gi-wave state (waves 8..11) ----
  const int sIdx = tid - 512;                    // [0,256) for gi waves
  const int jc0  = (wave-8)*32 + lh;             // triplet 2*gw
  const int jc1  = jc0 + 16;                     // triplet 2*gw+1
  const int wrow = (sIdx>>4)&15, wcol=(sIdx&15)*8;
  int lenW = 0;
  if (!ghR) lenW = lengths[b0 + wrow];

  // stage one x unit: linear in [0, 3*512), slot = linear>>9, step = base+slot
  auto stageB = [&](int linear, int baseStep){
    const int slot = linear>>9;
    const int idx  = linear&511;
    const int srow = idx>>5;
    const int sabs = baseStep + slot;
    const int ls   = lengths[b0+srow];
    int tb = dir ? ls-1-sabs : sabs;
    tb = tb<0 ? 0 : (tb>511 ? 511 : tb);
    if constexpr (F32IN){
      const int scol = idx&31;
      float v = ((const float*)seqIn_)[((size_t)(b0+srow)*512+tb)*32 + scol];
      bf16 hh=(bf16)v;
      xb[slot*XSLOT + srow*XSTR + scol] = hh;
      xb[slot*XSLOT + XPL + srow*XSTR + scol] = (bf16)(v-(float)hh);
    } else {
      const int sblk = idx&31;
      bf16x8 v = *(const bf16x8*)((const bf16*)seqIn_ + ((size_t)(b0+srow)*512+tb)*256 + sblk*8);
      *(bf16x8*)&xb[slot*XSLOT + srow*XSTR + sblk*8] = v;
    }
  };

  // gi sweep: compute gi for steps base..base+3 into ring slots (base+i)%5.
  // x: slots 0..2 from LDS, step base+3 directly from global.
  auto sweep = [&](int base){
    const int s3 = base+3;
    int tb3 = dir ? lenA-1-s3 : s3;
    tb3 = tb3<0 ? 0 : (tb3>511 ? 511 : tb3);
    const int r0=(base)%5, r1=(base+1)%5, r2=(base+2)%5, r3=(base+3)%5;
#pragma unroll
    for (int tg=0; tg<6; ++tg){
      const int col = ((tg<3)? jc0 : jc1) + (tg%3)*128;
      const bf16* bHp = WihHi + (size_t)col*KIN;
      const bf16* bLp = WihLo + (size_t)col*KIN;
      f32x4 a0=Z4,a1=Z4,a2=Z4,a3=Z4;
#pragma unroll
      for (int ks=0;ks<NKS;++ks){
        const int o = ks*32 + quad*8;
        bf16x8 bH = *(const bf16x8*)(bHp + o);
        bf16x8 bL = *(const bf16x8*)(bLp + o);
        if constexpr (F32IN){
          bf16x8 xh, xl;
          xh = *(const bf16x8*)&xb[0*XSLOT + lh*XSTR + o];
          xl = *(const bf16x8*)&xb[0*XSLOT + XPL + lh*XSTR + o];
          a0=MFMA(xh,bH,a0); a0=MFMA(xl,bH,a0); a0=MFMA(xh,bL,a0);
          xh = *(const bf16x8*)&xb[1*XSLOT + lh*XSTR + o];
          xl = *(const bf16x8*)&xb[1*XSLOT + XPL + lh*XSTR + o];
          a1=MFMA(xh,bH,a1); a1=MFMA(xl,bH,a1); a1=MFMA(xh,bL,a1);
          xh = *(const bf16x8*)&xb[2*XSLOT + lh*XSTR + o];
          xl = *(const bf16x8*)&xb[2*XSLOT + XPL + lh*XSTR + o];
          a2=MFMA(xh,bH,a2); a2=MFMA(xl,bH,a2); a2=MFMA(xh,bL,a2);
          const float* xp = (const float*)seqIn_ + ((size_t)(b0+lh)*512+tb3)*KIN + o;
          bf16x8 x3h, x3l;
#pragma unroll
          for (int e=0;e<8;++e){ float v=xp[e]; bf16 hh=(bf16)v; x3h[e]=hh; x3l[e]=(bf16)(v-(float)hh); }
          a3=MFMA(x3h,bH,a3); a3=MFMA(x3l,bH,a3); a3=MFMA(x3h,bL,a3);
        } else {
          bf16x8 x0 = *(const bf16x8*)&xb[0*XSLOT + lh*XSTR + o];
          a0=MFMA(x0,bH,a0); a0=MFMA(x0,bL,a0);
          bf16x8 x1 = *(const bf16x8*)&xb[1*XSLOT + lh*XSTR + o];
          a1=MFMA(x1,bH,a1); a1=MFMA(x1,bL,a1);
          bf16x8 x2 = *(const bf16x8*)&xb[2*XSLOT + lh*XSTR + o];
          a2=MFMA(x2,bH,a2); a2=MFMA(x2,bL,a2);
          bf16x8 x3 = *(const bf16x8*)((const bf16*)seqIn_ + ((size_t)(b0+lh)*512+tb3)*KIN + o);
          a3=MFMA(x3,bH,a3); a3=MFMA(x3,bL,a3);
        }
      }
#pragma unroll
      for (int r=0;r<4;++r){
        const int m = quad*4+r;
        ring[r0*6144 + m*384 + col] = a0[r];
        ring[r1*6144 + m*384 + col] = a1[r];
        ring[r2*6144 + m*384 + col] = a2[r];
        ring[r3*6144 + m*384 + col] = a3[r];
      }
    }
  };

  // ---- prologue: stage x for steps 0..2, sweep gi(0..3) ----
  if (!ghR){
#pragma unroll
    for (int u=0;u<6;++u) stageB(u*256 + sIdx, 0);
  }
  __syncthreads();
  if (!ghR) sweep(0);
  __syncthreads();

  // ---- main loop ----
  for (int t4=0; t4<TT; t4+=4){
#pragma unroll
    for (int p=0;p<4;++p){
      const int t = t4+p;
      float hsel[4];
      if (ghR){
        // gh MFMAs on h(t-1) (resident Whh)
        f32x4 gR=Z4, gZ=Z4, gN=Z4;
#pragma unroll
        for (int ks=0;ks<4;++ks){
          bf16x8 aH = *(const bf16x8*)&hHi[lh*136 + ks*32 + quad*8];
          bf16x8 aL = *(const bf16x8*)&hLo[lh*136 + ks*32 + quad*8];
          gR=MFMA(aH,wRH[ks],gR); gR=MFMA(aL,wRH[ks],gR); gR=MFMA(aH,wRL[ks],gR);
          gZ=MFMA(aH,wZH[ks],gZ); gZ=MFMA(aL,wZH[ks],gZ); gZ=MFMA(aH,wZL[ks],gZ);
          gN=MFMA(aH,wNH[ks],gN); gN=MFMA(aL,wNH[ks],gN); gN=MFMA(aH,wNL[ks],gN);
        }
        const int rs = t%5;
#pragma unroll
        for (int r=0;r<4;++r){
          const int m = quad*4+r;
          const float giR = ring[rs*6144 + m*384 + cR];
          const float giZ = ring[rs*6144 + m*384 + cZ];
          const float giN = ring[rs*6144 + m*384 + cN];
          float rr = sigm_(gR[r] + giR + bR);
          float zz = sigm_(gZ[r] + giZ + bZ);
          float nn = tanh_(giN + bNi + rr*(gN[r] + bNh));
          float hold = (float)hHi[m*136+jc] + (float)hLo[m*136+jc];
          float hnew = fin_((1.f-zz)*nn + zz*hold);
          hsel[r] = (t < lenRow[r]) ? hnew : hold;
        }
      } else {
        // seqOut writer for h(t-1)
        if (seqOut && t>0 && (t-1)<lenW){
          const int tp = t-1;
          const int tb = dir ? (lenW-1-tp) : tp;
          bf16x8 v = *(const bf16x8*)&hHi[wrow*136 + wcol];
          *(bf16x8*)(seqOut + ((size_t)(b0+wrow)*512 + tb)*256 + dir*128 + wcol) = v;
        }
        if (p==0){
#pragma unroll
          for (int u=0;u<4;++u) stageB(u*256 + sIdx, t4+4);        // slots 0,1
        } else if (p==1){
#pragma unroll
          for (int u=0;u<2;++u) stageB(1024 + u*256 + sIdx, t4+4); // slot 2
        } else if (p==3){
          // sweep at p==3: writes {t4+4,t4,t4+1,t4+2}%5; reader this phase uses
          // (t4+3)%5 — disjoint (the p==2 placement collided: t4+7 == t4+2 mod 5)
          sweep(t4+4);
        }
      }
      __syncthreads();   // B1: h(t-1) reads done; ring/xb writes visible
      if (ghR){
#pragma unroll
        for (int r=0;r<4;++r){
          const int m = quad*4+r;
          bf16 hi = (bf16)hsel[r];
          hHi[m*136+jc] = hi;
          hLo[m*136+jc] = (bf16)(hsel[r]-(float)hi);
        }
      }
      __syncthreads();   // B2: h(t) visible
    }
  }

  // epilogue
  if (!ghR){
    if (seqOut && (TT-1)<lenW){
      const int tb = dir ? (lenW-1-(TT-1)) : (TT-1);
      bf16x8 v = *(const bf16x8*)&hHi[wrow*136 + wcol];
      *(bf16x8*)(seqOut + ((size_t)(b0+wrow)*512 + tb)*256 + dir*128 + wcol) = v;
    }
    float* hout = dir ? hBo : hFo;
    if (hout){
#pragma unroll
      for (int e=0;e<8;++e){
        const int j = wcol+e;
        hout[(size_t)(b0+wrow)*128 + j] = fin_((float)hHi[wrow*136+j] + (float)hLo[wrow*136+j]);
      }
    }
  }
}

// ---------------------------------------------------------------------------
// Latent: mean/logvar/z/h_init. grid=256, block=64. fp32.
// ---------------------------------------------------------------------------
__global__ void latent_k(const float* __restrict__ hF, const float* __restrict__ hB,
                         const float* __restrict__ eps,
                         const float* __restrict__ Wm, const float* __restrict__ bm,
                         const float* __restrict__ Wl, const float* __restrict__ bl,
                         const float* __restrict__ Wz, const float* __restrict__ bz,
                         float* __restrict__ out_mean, float* __restrict__ out_logvar,
                         float* __restrict__ hInit)
{
  const int b = blockIdx.x, tid = threadIdx.x;
  __shared__ float hc[256];
  __shared__ float mv[64];
  __shared__ float zz[32];
  for (int k=tid;k<256;k+=64) hc[k] = fin_((k<128)? hF[(size_t)b*128+k] : hB[(size_t)b*128+k-128]);
  __syncthreads();
  {
    const int i = tid & 31;
    const float* W = (tid<32)? Wm : Wl;
    float acc = (tid<32)? bm[i] : bl[i];
    for (int k=0;k<256;++k) acc += hc[k]*W[i*256+k];
    acc = fin_(acc);
    mv[tid] = acc;
    if (tid<32) out_mean[b*32+i] = acc;
    else        out_logvar[b*32+(tid-32)] = acc;
  }
  __syncthreads();
  if (tid<32) zz[tid] = fin_(mv[tid] + __expf(0.5f*mv[32+tid]) * eps[b*32+tid]);
  __syncthreads();
  for (int j=tid;j<128;j+=64){
    float a = bz[j];
    for (int k=0;k<32;++k) a += zz[k]*Wz[j*32+k];
    hInit[(size_t)b*128 + j] = tanh_(fin_(a));
  }
}

// ---------------------------------------------------------------------------
// Decoder: 2-layer GRU + out-proj, T=512. grid=16, block=512 (8 waves).
// R7 structure; waves_per_eu(2,2) forces the 256-VGPR budget so pinned
// W0h/W1h actually live in arch VGPRs.
// ---------------------------------------------------------------------------
__global__ __launch_bounds__(512) __attribute__((amdgpu_waves_per_eu(2,2)))
void dec_rec(const float* __restrict__ hInit,
             const bf16* __restrict__ W0iH, const bf16* __restrict__ W0iL,  // [384,32]
             const bf16* __restrict__ W0hH, const bf16* __restrict__ W0hL,  // [384,128]
             const bf16* __restrict__ W1iH, const bf16* __restrict__ W1iL,  // [384,128]
             const bf16* __restrict__ W1hH, const bf16* __restrict__ W1hL,  // [384,128]
             const bf16* __restrict__ WoH,  const bf16* __restrict__ WoL,   // [32,128]
             const float* __restrict__ bih0, const float* __restrict__ bhh0,
             const float* __restrict__ bih1, const float* __restrict__ bhh1,
             const float* __restrict__ bout,
             float* __restrict__ rec)        // [256,512,32]
{
  const int tid = threadIdx.x;
  const int wave = tid>>6;
  const int lh   = tid&15;
  const int quad = (tid>>4)&3;
  const int b0 = blockIdx.x*16;
  const int jc = wave*16 + lh;
  const int cR = jc, cZ = 128+jc, cN = 256+jc;

  __shared__ bf16 h1H[16*136], h1L[16*136], h2H[16*136], h2L[16*136];
  __shared__ bf16 pH[16*40], pL[16*40];
  __shared__ bf16 w1iLds[384*136];   // W1i-hi plane, stride-136 padded

  bf16x8 a0RH[4],a0RL[4],a0ZH[4],a0ZL[4],a0NH[4],a0NL[4];
  bf16x8 a1RH[4],a1RL[4],a1ZH[4],a1ZL[4],a1NH[4],a1NL[4];
#pragma unroll
  for (int ks=0;ks<4;++ks){
    const int o = ks*32 + quad*8;
    a0RH[ks]=*(const bf16x8*)(W0hH+(size_t)cR*128+o); a0RL[ks]=*(const bf16x8*)(W0hL+(size_t)cR*128+o);
    a0ZH[ks]=*(const bf16x8*)(W0hH+(size_t)cZ*128+o); a0ZL[ks]=*(const bf16x8*)(W0hL+(size_t)cZ*128+o);
    a0NH[ks]=*(const bf16x8*)(W0hH+(size_t)cN*128+o); a0NL[ks]=*(const bf16x8*)(W0hL+(size_t)cN*128+o);
    a1RH[ks]=*(const bf16x8*)(W1hH+(size_t)cR*128+o); a1RL[ks]=*(const bf16x8*)(W1hL+(size_t)cR*128+o);
    a1ZH[ks]=*(const bf16x8*)(W1hH+(size_t)cZ*128+o); a1ZL[ks]=*(const bf16x8*)(W1hL+(size_t)cZ*128+o);
    a1NH[ks]=*(const bf16x8*)(W1hH+(size_t)cN*128+o); a1NL[ks]=*(const bf16x8*)(W1hL+(size_t)cN*128+o);
    pin_(a0RH[ks]); pin_(a0RL[ks]); pin_(a0ZH[ks]); pin_(a0ZL[ks]); pin_(a0NH[ks]); pin_(a0NL[ks]);
    pin_(a1RH[ks]); pin_(a1RL[ks]); pin_(a1ZH[ks]); pin_(a1ZL[ks]); pin_(a1NH[ks]); pin_(a1NL[ks]);
  }
  const float b1R = bih0[cR]+bhh0[cR], b1Z = bih0[cZ]+bhh0[cZ], b1Ni = bih0[cN], b1Nh = bhh0[cN];
  const float b2R = bih1[cR]+bhh1[cR], b2Z = bih1[cZ]+bhh1[cZ], b2Ni = bih1[cN], b2Nh = bhh1[cN];
  const float bo = (wave<2) ? bout[wave*16+lh] : 0.f;

  for (int i=tid; i<384*16; i+=512){
    const int rr = i>>4, k8 = (i&15)*8;
    *(bf16x8*)&w1iLds[rr*136 + k8] = *(const bf16x8*)(W1iH + (size_t)rr*128 + k8);
  }
  if (tid < 256){
    const int row = (tid>>4)&15;
    const int c0  = (tid&15)*8;
#pragma unroll
    for (int e=0;e<8;++e){
      const int j = c0+e;
      float v = fin_(hInit[(size_t)(b0+row)*128 + j]);
      bf16 hi=(bf16)v, lo=(bf16)(v-(float)hi);
      h1H[row*136+j]=hi; h1L[row*136+j]=lo;
      h2H[row*136+j]=hi; h2L[row*136+j]=lo;
    }
  }
  for (int i=tid;i<16*40;i+=512){ pH[i]=(bf16)0.f; pL[i]=(bf16)0.f; }
  __syncthreads();

  f32x4 c1R, c1Z, c1Nh, c2R, c2Z, c2Nh;

  auto ghpre = [&](){
    c1R=Z4; c1Z=Z4; c1Nh=Z4; c2R=Z4; c2Z=Z4; c2Nh=Z4;
#pragma unroll
    for (int ks=0;ks<4;++ks){
      const int o = ks*32 + quad*8;
      bf16x8 aH = *(const bf16x8*)&h1H[lh*136 + o];
      bf16x8 aL = *(const bf16x8*)&h1L[lh*136 + o];
      c1R =MFMA(aH,a0RH[ks],c1R);  c1R =MFMA(aL,a0RH[ks],c1R);  c1R =MFMA(aH,a0RL[ks],c1R);
      c1Z =MFMA(aH,a0ZH[ks],c1Z);  c1Z =MFMA(aL,a0ZH[ks],c1Z);  c1Z =MFMA(aH,a0ZL[ks],c1Z);
      c1Nh=MFMA(aH,a0NH[ks],c1Nh); c1Nh=MFMA(aL,a0NH[ks],c1Nh); c1Nh=MFMA(aH,a0NL[ks],c1Nh);
    }
#pragma unroll
    for (int ks=0;ks<4;++ks){
      const int o = ks*32 + quad*8;
      bf16x8 aH = *(const bf16x8*)&h2H[lh*136 + o];
      bf16x8 aL = *(const bf16x8*)&h2L[lh*136 + o];
      c2R =MFMA(aH,a1RH[ks],c2R);  c2R =MFMA(aL,a1RH[ks],c2R);  c2R =MFMA(aH,a1RL[ks],c2R);
      c2Z =MFMA(aH,a1ZH[ks],c2Z);  c2Z =MFMA(aL,a1ZH[ks],c2Z);  c2Z =MFMA(aH,a1ZL[ks],c2Z);
      c2Nh=MFMA(aH,a1NH[ks],c2Nh); c2Nh=MFMA(aL,a1NH[ks],c2Nh); c2Nh=MFMA(aH,a1NL[ks],c2Nh);
    }
  };
  ghpre();

  for (int t=0;t<512;++t){
    // ---- P1: gi1 (pred, K=32) + gates1 + write h1(t) ----
    {
      f32x4 c1Ni = Z4;
      bf16x8 aP0 = *(const bf16x8*)&pH[lh*40 + quad*8];
      bf16x8 aP1 = *(const bf16x8*)&pL[lh*40 + quad*8];
      const int o = quad*8;
      bf16x8 bH,bL;
      bH=*(const bf16x8*)(W0iH+(size_t)cR*32+o); bL=*(const bf16x8*)(W0iL+(size_t)cR*32+o);
      c1R=MFMA(aP0,bH,c1R); c1R=MFMA(aP1,bH,c1R); c1R=MFMA(aP0,bL,c1R);
      bH=*(const bf16x8*)(W0iH+(size_t)cZ*32+o); bL=*(const bf16x8*)(W0iL+(size_t)cZ*32+o);
      c1Z=MFMA(aP0,bH,c1Z); c1Z=MFMA(aP1,bH,c1Z); c1Z=MFMA(aP0,bL,c1Z);
      bH=*(const bf16x8*)(W0iH+(size_t)cN*32+o); bL=*(const bf16x8*)(W0iL+(size_t)cN*32+o);
      c1Ni=MFMA(aP0,bH,c1Ni); c1Ni=MFMA(aP1,bH,c1Ni); c1Ni=MFMA(aP0,bL,c1Ni);
#pragma unroll
      for (int r=0;r<4;++r){
        const int m = quad*4+r;
        float rr = sigm_(c1R[r] + b1R);
        float z  = sigm_(c1Z[r] + b1Z);
        float nn = tanh_(c1Ni[r] + b1Ni + rr*(c1Nh[r] + b1Nh));
        float hold = (float)h1H[m*136+jc] + (float)h1L[m*136+jc];
        float hnew = fin_((1.f-z)*nn + z*hold);
        bf16 hi=(bf16)hnew;
        h1H[m*136+jc]=hi; h1L[m*136+jc]=(bf16)(hnew-(float)hi);
      }
    }
    __syncthreads();                       // B1: h1(t) visible
    // ---- P2: gi2 (h1(t), K=128) + gates2 + write h2(t) ----
    {
      f32x4 c2Ni = Z4;
#pragma unroll
      for (int ks=0;ks<4;++ks){
        const int o = ks*32 + quad*8;
        bf16x8 aH = *(const bf16x8*)&h1H[lh*136 + o];
        bf16x8 aL = *(const bf16x8*)&h1L[lh*136 + o];
        bf16x8 bH,bL;
        bH=*(const bf16x8*)&w1iLds[cR*136+o]; bL=*(const bf16x8*)(W1iL+(size_t)cR*128+o);
        c2R=MFMA(aH,bH,c2R); c2R=MFMA(aL,bH,c2R); c2R=MFMA(aH,bL,c2R);
        bH=*(const bf16x8*)&w1iLds[cZ*136+o]; bL=*(const bf16x8*)(W1iL+(size_t)cZ*128+o);
        c2Z=MFMA(aH,bH,c2Z); c2Z=MFMA(aL,bH,c2Z); c2Z=MFMA(aH,bL,c2Z);
        bH=*(const bf16x8*)&w1iLds[cN*136+o]; bL=*(const bf16x8*)(W1iL+(size_t)cN*128+o);
        c2Ni=MFMA(aH,bH,c2Ni); c2Ni=MFMA(aL,bH,c2Ni); c2Ni=MFMA(aH,bL,c2Ni);
      }
#pragma unroll
      for (int r=0;r<4;++r){
        const int m = quad*4+r;
        float rr = sigm_(c2R[r] + b2R);
        float z  = sigm_(c2Z[r] + b2Z);
        float nn = tanh_(c2Ni[r] + b2Ni + rr*(c2Nh[r] + b2Nh));
        float hold = (float)h2H[m*136+jc] + (float)h2L[m*136+jc];
        float hnew = fin_((1.f-z)*nn + z*hold);
        bf16 hi=(bf16)hnew;
        h2H[m*136+jc]=hi; h2L[m*136+jc]=(bf16)(hnew-(float)hi);
      }
    }
    __syncthreads();                       // B2: h2(t) visible
    // ---- P3: out-proj (waves 0,1) + gh precompute for t+1 ----
    if (wave<2){
      f32x4 po=Z4;
#pragma unroll
      for (int ks=0;ks<4;++ks){
        const int o = ks*32 + quad*8;
        bf16x8 oH = *(const bf16x8*)&h2H[lh*136 + o];
        bf16x8 oL = *(const bf16x8*)&h2L[lh*136 + o];
        bf16x8 bH = *(const bf16x8*)(WoH + (size_t)(wave*16+lh)*128 + o);
        bf16x8 bL = *(const bf16x8*)(WoL + (size_t)(wave*16+lh)*128 + o);
        po=MFMA(oH,bH,po); po=MFMA(oL,bH,po); po=MFMA(oH,bL,po);
      }
#pragma unroll
      for (int r=0;r<4;++r){
        const int m = quad*4+r;
        float pv = fin_(po[r]+bo);
        rec[((size_t)(b0+m)*512 + t)*32 + wave*16+lh] = pv;
        bf16 hi=(bf16)pv;
        pH[m*40 + wave*16+lh]=hi; pL[m*40 + wave*16+lh]=(bf16)(pv-(float)hi);
      }
    }
    if (t+1 < 512) ghpre();
    __syncthreads();                       // B3: pred(t) visible
  }
}

// ---------------------------------------------------------------------------
extern "C" void kernel_launch(void* const* d_in, const int* in_sizes, int n_in,
                              void* d_out, int out_size, void* d_ws, size_t ws_size,
                              hipStream_t stream)
{
  const float* x       = (const float*)d_in[0];
  const int*   lengths = (const int*)d_in[1];
  const float* eps     = (const float*)d_in[2];
  const float* eWih0   = (const float*)d_in[3];
  const float* eWhh0   = (const float*)d_in[4];
  const float* ebih0   = (const float*)d_in[5];
  const float* ebhh0   = (const float*)d_in[6];
  const float* eWih12  = (const float*)d_in[7];
  const float* eWhh12  = (const float*)d_in[8];
  const float* ebih12  = (const float*)d_in[9];
  const float* ebhh12  = (const float*)d_in[10];
  const float* dWih0   = (const float*)d_in[11];
  const float* dWhh0   = (const float*)d_in[12];
  const float* dbih0   = (const float*)d_in[13];
  const float* dbhh0   = (const float*)d_in[14];
  const float* dWih1   = (const float*)d_in[15];
  const float* dWhh1   = (const float*)d_in[16];
  const float* dbih1   = (const float*)d_in[17];
  const float* dbhh1   = (const float*)d_in[18];
  const float* Wm      = (const float*)d_in[19];
  const float* bm      = (const float*)d_in[20];
  const float* Wl      = (const float*)d_in[21];
  const float* bl      = (const float*)d_in[22];
  const float* Wz      = (const float*)d_in[23];
  const float* bz      = (const float*)d_in[24];
  const float* Wo      = (const float*)d_in[25];
  const float* bo      = (const float*)d_in[26];

  char* ws = (char*)d_ws;
  bf16* P     = (bf16*)ws;
  bf16* seqA  = (bf16*)(ws + (size_t)(4<<20));
  bf16* seqB  = (bf16*)(ws + (size_t)(68<<20));
  float* hF    = (float*)seqA;
  float* hB    = hF + 256*128;
  float* hInit = hB + 256*128;

  const size_t O_eWih0  = 0;
  const size_t O_eWhh0  = 49152;
  const size_t O_eWih12 = 245760;
  const size_t O_eWhh12 = 1032192;
  const size_t O_dWih0  = 1425408;
  const size_t O_dWhh0  = 1449984;
  const size_t O_dWih1  = 1548288;
  const size_t O_dWhh1  = 1646592;
  const size_t O_Wout   = 1744896;

  float* out   = (float*)d_out;
  float* rec   = out;
  float* omean = out + (size_t)4194304;
  float* ologv = omean + 8192;

  size_t zoff = (size_t)(4<<20);
  size_t zbytes = (size_t)(128<<20);
  if (zoff + zbytes > ws_size) zbytes = (ws_size > zoff)? ws_size - zoff : 0;
  hipMemsetAsync(ws + zoff, 0, zbytes, stream);

  PrepJobs J;
  const float* srcs[9] = {eWih0, eWhh0, eWih12, eWhh12, dWih0, dWhh0, dWih1, dWhh1, Wo};
  const size_t offs[9] = {O_eWih0,O_eWhh0,O_eWih12,O_eWhh12,O_dWih0,O_dWhh0,O_dWih1,O_dWhh1,O_Wout};
  const int    ns[9]   = {24576, 98304, 393216, 196608, 12288, 49152, 49152, 49152, 4096};
  for (int j=0;j<9;++j){ J.src[j]=srcs[j]; J.hi[j]=P+offs[j]; J.lo[j]=P+offs[j]+ns[j]; J.n[j]=ns[j]; }
  prep_w<<<256, 256, 0, stream>>>(J);

  dim3 blkE(768), blkD(512);

  enc_rec<32,true><<<32, blkE, 0, stream>>>(x, seqA,
      P+O_eWih0, P+O_eWih0+24576, P+O_eWhh0, P+O_eWhh0+98304,
      ebih0, ebhh0, lengths, nullptr, nullptr);
  enc_rec<256,false><<<32, blkE, 0, stream>>>(seqA, seqB,
      P+O_eWih12, P+O_eWih12+393216, P+O_eWhh12, P+O_eWhh12+196608,
      ebih12, ebhh12, lengths, nullptr, nullptr);
  enc_rec<256,false><<<32, blkE, 0, stream>>>(seqB, nullptr,
      P+O_eWih12+196608, P+O_eWih12+393216+196608,
      P+O_eWhh12+98304,  P+O_eWhh12+196608+98304,
      ebih12+768, ebhh12+768, lengths, hF, hB);
  latent_k<<<256, 64, 0, stream>>>(hF, hB, eps, Wm, bm, Wl, bl, Wz, bz,
                                   omean, ologv, hInit);
  dec_rec<<<16, blkD, 0, stream>>>(hInit,
      P+O_dWih0, P+O_dWih0+12288, P+O_dWhh0, P+O_dWhh0+49152,
      P+O_dWih1, P+O_dWih1+49152, P+O_dWhh1, P+O_dWhh1+49152,
      P+O_Wout,  P+O_Wout+4096,
      dbih0, dbhh0, dbih1, dbhh1, bo, rec);
}

// Round 10
// 10063.837 us; speedup vs baseline: 2.1424x; 2.1424x over previous
//
#include <hip/hip_runtime.h>
#include <hip/hip_bf16.h>

// VRAE forward on gfx950. FP32 I/O; MFMA via bf16 hi/lo planes (~fp32 accuracy).
// R10 = R7 structure (best measured: 9.8ms) with ONE change: resident weight
// fragments pinned into AGPRs ("+a" asm constraint) instead of VGPRs.
// Evidence: R6/R7/R9 all show the allocator caps arch VGPRs at ~128 and
// remats/spills pinned "+v" values (VGPR_Count stayed 84-128; dur flat).
// gfx950 MFMA reads A/B from VGPR OR AGPR (unified file, isa §10); AGPRs are
// outside the VALU-pressure heuristic -> true residency for loop-invariant
// Whh (enc, 96 regs) and W0h/W1h (dec, 192 regs). R8/R9's dedicated-gi-wave
// encoder REGRESSED (6.9ms/layer vs R7 1.7ms) and is abandoned.

typedef __bf16 bf16;
typedef __bf16 bf16x8 __attribute__((ext_vector_type(8)));
typedef float f32x4 __attribute__((ext_vector_type(4)));

#define MFMA(a,b,c) __builtin_amdgcn_mfma_f32_16x16x32_bf16((a),(b),(c),0,0,0)
#define Z4 (f32x4){0.f,0.f,0.f,0.f}

__device__ __forceinline__ float sigm_(float x){ return 1.f/(1.f+__expf(-x)); }
__device__ __forceinline__ float tanh_(float x){
  x = fminf(15.f, fmaxf(-15.f, x));
  float e = __expf(2.f*x);
  return (e-1.f)/(e+1.f);
}
__device__ __forceinline__ float fin_(float v){ return (v - v == 0.0f) ? v : 0.0f; }
// AGPR pin: forces the value into accumulator registers, which the VGPR
// pressure heuristic does not evict. MFMA can consume A/B from AGPR directly.
__device__ __forceinline__ void pin_(bf16x8 &v){ asm volatile("" : "+a"(v)); }

// ---------------------------------------------------------------------------
// Weight prep: fp32 -> bf16 hi/lo planes in ws.
// ---------------------------------------------------------------------------
struct PrepJobs {
  const float* src[9];
  bf16* hi[9];
  bf16* lo[9];
  int n[9];
};

__global__ void prep_w(PrepJobs J){
  const int stride = gridDim.x*blockDim.x;
  const int t0 = blockIdx.x*blockDim.x + threadIdx.x;
  for (int j=0;j<9;++j){
    const float* __restrict__ s = J.src[j];
    bf16* __restrict__ h = J.hi[j];
    bf16* __restrict__ l = J.lo[j];
    const int n = J.n[j];
    for (int i=t0;i<n;i+=stride){
      float v = fin_(s[i]);
      bf16 hh = (bf16)v;
      h[i] = hh;
      l[i] = (bf16)(v - (float)hh);
    }
  }
}

// ---------------------------------------------------------------------------
// Encoder recurrent kernel. grid=32: blockIdx>>4 = dir, blockIdx&15 = batch
// slice of 16. block=512 (8 waves). Wave w owns gate triplet {w,8+w,16+w}.
// Whh hi/lo AGPR-resident; Wih swept once per 4 steps (gi burst).
// ---------------------------------------------------------------------------
template<int KIN, bool F32IN>
__global__ __launch_bounds__(512,2)
void enc_rec(const void* __restrict__ seqIn_,  // [256,512,KIN] fp32|bf16
             bf16* __restrict__ seqOut,        // [256,512,256] or null
             const bf16* __restrict__ WihHi_, const bf16* __restrict__ WihLo_, // [2,384,KIN]
             const bf16* __restrict__ WhhHi_, const bf16* __restrict__ WhhLo_, // [2,384,128]
             const float* __restrict__ bih_, const float* __restrict__ bhh_,   // [2,384]
             const int* __restrict__ lengths,
             float* __restrict__ hFo, float* __restrict__ hBo)                 // [256,128] or null
{
  constexpr int NKS  = KIN/32;
  constexpr int XSTR = F32IN ? 40 : 264;
  constexpr int XPL  = 16*XSTR;
  constexpr int XSLOT= (F32IN?2:1)*XPL;
  const int tid = threadIdx.x;
  const int wave = tid>>6;
  const int lh   = tid&15;
  const int quad = (tid>>4)&3;
  const int dir  = blockIdx.x>>4;
  const int b0   = (blockIdx.x&15)*16;

  const bf16* __restrict__ WihHi = WihHi_ + (size_t)dir*384*KIN;
  const bf16* __restrict__ WihLo = WihLo_ + (size_t)dir*384*KIN;
  const bf16* __restrict__ WhhHi = WhhHi_ + (size_t)dir*384*128;
  const bf16* __restrict__ WhhLo = WhhLo_ + (size_t)dir*384*128;
  const float* __restrict__ bih = bih_ + dir*384;
  const float* __restrict__ bhh = bhh_ + dir*384;

  __shared__ bf16 hHi[16*136], hLo[16*136];
  __shared__ bf16 xb[4*XSLOT];

  const int jc = wave*16 + lh;
  const int cR = jc, cZ = 128+jc, cN = 256+jc;

  // resident Whh hi/lo frags (24 frags = 96 regs) — AGPR-pinned
  bf16x8 wRH[4],wRL[4],wZH[4],wZL[4],wNH[4],wNL[4];
#pragma unroll
  for (int ks=0;ks<4;++ks){
    const int o = ks*32 + quad*8;
    wRH[ks]=*(const bf16x8*)(WhhHi+(size_t)cR*128+o); wRL[ks]=*(const bf16x8*)(WhhLo+(size_t)cR*128+o);
    wZH[ks]=*(const bf16x8*)(WhhHi+(size_t)cZ*128+o); wZL[ks]=*(const bf16x8*)(WhhLo+(size_t)cZ*128+o);
    wNH[ks]=*(const bf16x8*)(WhhHi+(size_t)cN*128+o); wNL[ks]=*(const bf16x8*)(WhhLo+(size_t)cN*128+o);
    pin_(wRH[ks]); pin_(wRL[ks]); pin_(wZH[ks]); pin_(wZL[ks]); pin_(wNH[ks]); pin_(wNL[ks]);
  }
  const float bR  = bih[cR]+bhh[cR];
  const float bZc = bih[cZ]+bhh[cZ];
  const float bNi = bih[cN];
  const float bNh = bhh[cN];

  int lenRow[4];
#pragma unroll
  for (int r=0;r<4;++r) lenRow[r] = lengths[b0 + quad*4 + r];
  const int lenA = lengths[b0+lh];
  const int Tmax = lengths[b0];
  const int TT   = (Tmax+3)&~3;

  const int wrow = (tid>>4)&15;
  const int wcol = (tid&15)*8;
  const int lenW = lengths[b0 + wrow];
  const int srow = tid>>5;
  const int scol = tid&31;
  const int lenS = lengths[b0 + srow];

  for (int i=tid;i<16*136;i+=512){ hHi[i]=(bf16)0.f; hLo[i]=(bf16)0.f; }

  auto stage = [&](int slot, int sabs){
    int tb = dir ? (lenS-1-sabs) : sabs;
    tb = tb<0 ? 0 : (tb>511 ? 511 : tb);
    if constexpr (F32IN){
      float v = ((const float*)seqIn_)[((size_t)(b0+srow)*512+tb)*32 + scol];
      bf16 hh=(bf16)v;
      xb[slot*XSLOT + srow*XSTR + scol] = hh;
      xb[slot*XSLOT + XPL + srow*XSTR + scol] = (bf16)(v-(float)hh);
    } else {
      bf16x8 v = *(const bf16x8*)((const bf16*)seqIn_ + ((size_t)(b0+srow)*512+tb)*256 + scol*8);
      *(bf16x8*)&xb[slot*XSLOT + srow*XSTR + scol*8] = v;
    }
  };
#pragma unroll
  for (int s=0;s<4;++s) stage(s, 1+s);

  f32x4 accR[4], accZ[4], giN[4];
#pragma unroll
  for (int s=0;s<4;++s){ accR[s]=Z4; accZ[s]=Z4; giN[s]=Z4; }

  // prologue: gi(0) -> slot 3
  {
    int tb0 = dir ? (lenA-1) : 0; tb0 = tb0<0?0:tb0;
#pragma unroll
    for (int ks=0;ks<NKS;++ks){
      const int o = ks*32 + quad*8;
      bf16x8 axH, axL;
      if constexpr (F32IN){
        const float* ap = (const float*)seqIn_ + ((size_t)(b0+lh)*512+tb0)*KIN + o;
#pragma unroll
        for (int e=0;e<8;++e){ float v=ap[e]; bf16 hh=(bf16)v; axH[e]=hh; axL[e]=(bf16)(v-(float)hh); }
      } else {
        axH = *(const bf16x8*)((const bf16*)seqIn_ + ((size_t)(b0+lh)*512+tb0)*KIN + o);
      }
      bf16x8 bH, bL;
      bH=*(const bf16x8*)(WihHi+(size_t)cR*KIN+o); bL=*(const bf16x8*)(WihLo+(size_t)cR*KIN+o);
      accR[3]=MFMA(axH,bH,accR[3]); if constexpr(F32IN) accR[3]=MFMA(axL,bH,accR[3]); accR[3]=MFMA(axH,bL,accR[3]);
      bH=*(const bf16x8*)(WihHi+(size_t)cZ*KIN+o); bL=*(const bf16x8*)(WihLo+(size_t)cZ*KIN+o);
      accZ[3]=MFMA(axH,bH,accZ[3]); if constexpr(F32IN) accZ[3]=MFMA(axL,bH,accZ[3]); accZ[3]=MFMA(axH,bL,accZ[3]);
      bH=*(const bf16x8*)(WihHi+(size_t)cN*KIN+o); bL=*(const bf16x8*)(WihLo+(size_t)cN*KIN+o);
      giN[3]=MFMA(axH,bH,giN[3]);  if constexpr(F32IN) giN[3]=MFMA(axL,bH,giN[3]);  giN[3]=MFMA(axH,bL,giN[3]);
    }
  }
  __syncthreads();

  for (int t4=0; t4<TT; t4+=4){
#pragma unroll
    for (int p=0;p<4;++p){
      const int t = t4 + p;
      const int s = (p+3)&3;
      if (seqOut && tid<256 && t>0 && (t-1)<lenW){
        const int tp = t-1;
        const int tb = dir ? (lenW-1-tp) : tp;
        bf16x8 v = *(const bf16x8*)&hHi[wrow*136 + wcol];
        *(bf16x8*)(seqOut + ((size_t)(b0+wrow)*512 + tb)*256 + dir*128 + wcol) = v;
      }
      f32x4 gN = Z4;
#pragma unroll
      for (int ks=0;ks<4;++ks){
        bf16x8 aH = *(const bf16x8*)&hHi[lh*136 + ks*32 + quad*8];
        bf16x8 aL = *(const bf16x8*)&hLo[lh*136 + ks*32 + quad*8];
        accR[s]=MFMA(aH,wRH[ks],accR[s]); accR[s]=MFMA(aL,wRH[ks],accR[s]); accR[s]=MFMA(aH,wRL[ks],accR[s]);
        accZ[s]=MFMA(aH,wZH[ks],accZ[s]); accZ[s]=MFMA(aL,wZH[ks],accZ[s]); accZ[s]=MFMA(aH,wZL[ks],accZ[s]);
        gN     =MFMA(aH,wNH[ks],gN);      gN     =MFMA(aL,wNH[ks],gN);      gN     =MFMA(aH,wNL[ks],gN);
      }
      float hsel[4];
#pragma unroll
      for (int r=0;r<4;++r){
        const int m = quad*4 + r;
        float rr = sigm_(accR[s][r] + bR);
        float zz = sigm_(accZ[s][r] + bZc);
        float nn = tanh_(giN[s][r] + bNi + rr*(gN[r] + bNh));
        float hold = (float)hHi[m*136+jc] + (float)hLo[m*136+jc];
        float hnew = fin_((1.f-zz)*nn + zz*hold);
        hsel[r] = (t < lenRow[r]) ? hnew : hold;
      }
      if (p==0){
#pragma unroll
        for (int s2=0;s2<4;++s2){ accR[s2]=Z4; accZ[s2]=Z4; giN[s2]=Z4; }
#pragma unroll
        for (int ks=0;ks<NKS;++ks){
          const int o = ks*32 + quad*8;
          bf16x8 axH[4], axL[F32IN?4:1];
#pragma unroll
          for (int s2=0;s2<4;++s2){
            axH[s2] = *(const bf16x8*)&xb[s2*XSLOT + lh*XSTR + o];
            if constexpr (F32IN) axL[s2] = *(const bf16x8*)&xb[s2*XSLOT + XPL + lh*XSTR + o];
          }
          bf16x8 bH, bL;
          bH=*(const bf16x8*)(WihHi+(size_t)cR*KIN+o); bL=*(const bf16x8*)(WihLo+(size_t)cR*KIN+o);
#pragma unroll
          for (int s2=0;s2<4;++s2){
            accR[s2]=MFMA(axH[s2],bH,accR[s2]);
            if constexpr(F32IN) accR[s2]=MFMA(axL[s2],bH,accR[s2]);
            accR[s2]=MFMA(axH[s2],bL,accR[s2]);
          }
          bH=*(const bf16x8*)(WihHi+(size_t)cZ*KIN+o); bL=*(const bf16x8*)(WihLo+(size_t)cZ*KIN+o);
#pragma unroll
          for (int s2=0;s2<4;++s2){
            accZ[s2]=MFMA(axH[s2],bH,accZ[s2]);
            if constexpr(F32IN) accZ[s2]=MFMA(axL[s2],bH,accZ[s2]);
            accZ[s2]=MFMA(axH[s2],bL,accZ[s2]);
          }
          bH=*(const bf16x8*)(WihHi+(size_t)cN*KIN+o); bL=*(const bf16x8*)(WihLo+(size_t)cN*KIN+o);
#pragma unroll
          for (int s2=0;s2<4;++s2){
            giN[s2]=MFMA(axH[s2],bH,giN[s2]);
            if constexpr(F32IN) giN[s2]=MFMA(axL[s2],bH,giN[s2]);
            giN[s2]=MFMA(axH[s2],bL,giN[s2]);
          }
        }
      }
      __syncthreads();     // B1: all reads of h(t-1) done
#pragma unroll
      for (int r=0;r<4;++r){
        const int m = quad*4 + r;
        bf16 hi = (bf16)hsel[r];
        hHi[m*136+jc] = hi;
        hLo[m*136+jc] = (bf16)(hsel[r]-(float)hi);
      }
      if      (p==1){ stage(0, t4+5); stage(1, t4+6); }
      else if (p==2){ stage(2, t4+7); }
      else if (p==3){ stage(3, t4+8); }
      __syncthreads();     // B2: h(t) + staged x visible
    }
  }
  if (seqOut && tid<256 && (TT-1)<lenW){
    const int tb = dir ? (lenW-1-(TT-1)) : (TT-1);
    bf16x8 v = *(const bf16x8*)&hHi[wrow*136 + wcol];
    *(bf16x8*)(seqOut + ((size_t)(b0+wrow)*512 + tb)*256 + dir*128 + wcol) = v;
  }
  float* hout = dir ? hBo : hFo;
  if (hout && tid<256){
#pragma unroll
    for (int e=0;e<8;++e){
      const int j = wcol+e;
      hout[(size_t)(b0+wrow)*128 + j] = fin_((float)hHi[wrow*136+j] + (float)hLo[wrow*136+j]);
    }
  }
}

// ---------------------------------------------------------------------------
// Latent: mean/logvar/z/h_init. grid=256, block=64. fp32.
// ---------------------------------------------------------------------------
__global__ void latent_k(const float* __restrict__ hF, const float* __restrict__ hB,
                         const float* __restrict__ eps,
                         const float* __restrict__ Wm, const float* __restrict__ bm,
                         const float* __restrict__ Wl, const float* __restrict__ bl,
                         const float* __restrict__ Wz, const float* __restrict__ bz,
                         float* __restrict__ out_mean, float* __restrict__ out_logvar,
                         float* __restrict__ hInit)
{
  const int b = blockIdx.x, tid = threadIdx.x;
  __shared__ float hc[256];
  __shared__ float mv[64];
  __shared__ float zz[32];
  for (int k=tid;k<256;k+=64) hc[k] = fin_((k<128)? hF[(size_t)b*128+k] : hB[(size_t)b*128+k-128]);
  __syncthreads();
  {
    const int i = tid & 31;
    const float* W = (tid<32)? Wm : Wl;
    float acc = (tid<32)? bm[i] : bl[i];
    for (int k=0;k<256;++k) acc += hc[k]*W[i*256+k];
    acc = fin_(acc);
    mv[tid] = acc;
    if (tid<32) out_mean[b*32+i] = acc;
    else        out_logvar[b*32+(tid-32)] = acc;
  }
  __syncthreads();
  if (tid<32) zz[tid] = fin_(mv[tid] + __expf(0.5f*mv[32+tid]) * eps[b*32+tid]);
  __syncthreads();
  for (int j=tid;j<128;j+=64){
    float a = bz[j];
    for (int k=0;k<32;++k) a += zz[k]*Wz[j*32+k];
    hInit[(size_t)b*128 + j] = tanh_(fin_(a));
  }
}

// ---------------------------------------------------------------------------
// Decoder: 2-layer GRU + out-proj, T=512. grid=16, block=512 (8 waves).
// Wave w owns triplet {w,8+w,16+w}. W0h+W1h AGPR-resident; W1i-hi in LDS;
// 3 barriers/step; gh1/gh2 for step t+1 precomputed during out-proj phase.
// ---------------------------------------------------------------------------
__global__ __launch_bounds__(512,2)
void dec_rec(const float* __restrict__ hInit,
             const bf16* __restrict__ W0iH, const bf16* __restrict__ W0iL,  // [384,32]
             const bf16* __restrict__ W0hH, const bf16* __restrict__ W0hL,  // [384,128]
             const bf16* __restrict__ W1iH, const bf16* __restrict__ W1iL,  // [384,128]
             const bf16* __restrict__ W1hH, const bf16* __restrict__ W1hL,  // [384,128]
             const bf16* __restrict__ WoH,  const bf16* __restrict__ WoL,   // [32,128]
             const float* __restrict__ bih0, const float* __restrict__ bhh0,
             const float* __restrict__ bih1, const float* __restrict__ bhh1,
             const float* __restrict__ bout,
             float* __restrict__ rec)        // [256,512,32]
{
  const int tid = threadIdx.x;
  const int wave = tid>>6;
  const int lh   = tid&15;
  const int quad = (tid>>4)&3;
  const int b0 = blockIdx.x*16;
  const int jc = wave*16 + lh;
  const int cR = jc, cZ = 128+jc, cN = 256+jc;

  __shared__ bf16 h1H[16*136], h1L[16*136], h2H[16*136], h2L[16*136];
  __shared__ bf16 pH[16*40], pL[16*40];
  __shared__ bf16 w1iLds[384*136];   // W1i-hi plane, stride-136 padded

  // resident W0h, W1h hi/lo (48 frags = 192 regs) — AGPR-pinned
  bf16x8 a0RH[4],a0RL[4],a0ZH[4],a0ZL[4],a0NH[4],a0NL[4];
  bf16x8 a1RH[4],a1RL[4],a1ZH[4],a1ZL[4],a1NH[4],a1NL[4];
#pragma unroll
  for (int ks=0;ks<4;++ks){
    const int o = ks*32 + quad*8;
    a0RH[ks]=*(const bf16x8*)(W0hH+(size_t)cR*128+o); a0RL[ks]=*(const bf16x8*)(W0hL+(size_t)cR*128+o);
    a0ZH[ks]=*(const bf16x8*)(W0hH+(size_t)cZ*128+o); a0ZL[ks]=*(const bf16x8*)(W0hL+(size_t)cZ*128+o);
    a0NH[ks]=*(const bf16x8*)(W0hH+(size_t)cN*128+o); a0NL[ks]=*(const bf16x8*)(W0hL+(size_t)cN*128+o);
    a1RH[ks]=*(const bf16x8*)(W1hH+(size_t)cR*128+o); a1RL[ks]=*(const bf16x8*)(W1hL+(size_t)cR*128+o);
    a1ZH[ks]=*(const bf16x8*)(W1hH+(size_t)cZ*128+o); a1ZL[ks]=*(const bf16x8*)(W1hL+(size_t)cZ*128+o);
    a1NH[ks]=*(const bf16x8*)(W1hH+(size_t)cN*128+o); a1NL[ks]=*(const bf16x8*)(W1hL+(size_t)cN*128+o);
    pin_(a0RH[ks]); pin_(a0RL[ks]); pin_(a0ZH[ks]); pin_(a0ZL[ks]); pin_(a0NH[ks]); pin_(a0NL[ks]);
    pin_(a1RH[ks]); pin_(a1RL[ks]); pin_(a1ZH[ks]); pin_(a1ZL[ks]); pin_(a1NH[ks]); pin_(a1NL[ks]);
  }
  const float b1R = bih0[cR]+bhh0[cR], b1Z = bih0[cZ]+bhh0[cZ], b1Ni = bih0[cN], b1Nh = bhh0[cN];
  const float b2R = bih1[cR]+bhh1[cR], b2Z = bih1[cZ]+bhh1[cZ], b2Ni = bih1[cN], b2Nh = bhh1[cN];
  const float bo = (wave<2) ? bout[wave*16+lh] : 0.f;

  for (int i=tid; i<384*16; i+=512){
    const int rr = i>>4, k8 = (i&15)*8;
    *(bf16x8*)&w1iLds[rr*136 + k8] = *(const bf16x8*)(W1iH + (size_t)rr*128 + k8);
  }
  if (tid < 256){
    const int row = (tid>>4)&15;
    const int c0  = (tid&15)*8;
#pragma unroll
    for (int e=0;e<8;++e){
      const int j = c0+e;
      float v = fin_(hInit[(size_t)(b0+row)*128 + j]);
      bf16 hi=(bf16)v, lo=(bf16)(v-(float)hi);
      h1H[row*136+j]=hi; h1L[row*136+j]=lo;
      h2H[row*136+j]=hi; h2L[row*136+j]=lo;
    }
  }
  for (int i=tid;i<16*40;i+=512){ pH[i]=(bf16)0.f; pL[i]=(bf16)0.f; }
  __syncthreads();

  f32x4 c1R, c1Z, c1Nh, c2R, c2Z, c2Nh;

  auto ghpre = [&](){
    c1R=Z4; c1Z=Z4; c1Nh=Z4; c2R=Z4; c2Z=Z4; c2Nh=Z4;
#pragma unroll
    for (int ks=0;ks<4;++ks){
      const int o = ks*32 + quad*8;
      bf16x8 aH = *(const bf16x8*)&h1H[lh*136 + o];
      bf16x8 aL = *(const bf16x8*)&h1L[lh*136 + o];
      c1R =MFMA(aH,a0RH[ks],c1R);  c1R =MFMA(aL,a0RH[ks],c1R);  c1R =MFMA(aH,a0RL[ks],c1R);
      c1Z =MFMA(aH,a0ZH[ks],c1Z);  c1Z =MFMA(aL,a0ZH[ks],c1Z);  c1Z =MFMA(aH,a0ZL[ks],c1Z);
      c1Nh=MFMA(aH,a0NH[ks],c1Nh); c1Nh=MFMA(aL,a0NH[ks],c1Nh); c1Nh=MFMA(aH,a0NL[ks],c1Nh);
    }
#pragma unroll
    for (int ks=0;ks<4;++ks){
      const int o = ks*32 + quad*8;
      bf16x8 aH = *(const bf16x8*)&h2H[lh*136 + o];
      bf16x8 aL = *(const bf16x8*)&h2L[lh*136 + o];
      c2R =MFMA(aH,a1RH[ks],c2R);  c2R =MFMA(aL,a1RH[ks],c2R);  c2R =MFMA(aH,a1RL[ks],c2R);
      c2Z =MFMA(aH,a1ZH[ks],c2Z);  c2Z =MFMA(aL,a1ZH[ks],c2Z);  c2Z =MFMA(aH,a1ZL[ks],c2Z);
      c2Nh=MFMA(aH,a1NH[ks],c2Nh); c2Nh=MFMA(aL,a1NH[ks],c2Nh); c2Nh=MFMA(aH,a1NL[ks],c2Nh);
    }
  };
  ghpre();

  for (int t=0;t<512;++t){
    // ---- P1: gi1 (pred, K=32) + gates1 + write h1(t) ----
    {
      f32x4 c1Ni = Z4;
      bf16x8 aP0 = *(const bf16x8*)&pH[lh*40 + quad*8];
      bf16x8 aP1 = *(const bf16x8*)&pL[lh*40 + quad*8];
      const int o = quad*8;
      bf16x8 bH,bL;
      bH=*(const bf16x8*)(W0iH+(size_t)cR*32+o); bL=*(const bf16x8*)(W0iL+(size_t)cR*32+o);
      c1R=MFMA(aP0,bH,c1R); c1R=MFMA(aP1,bH,c1R); c1R=MFMA(aP0,bL,c1R);
      bH=*(const bf16x8*)(W0iH+(size_t)cZ*32+o); bL=*(const bf16x8*)(W0iL+(size_t)cZ*32+o);
      c1Z=MFMA(aP0,bH,c1Z); c1Z=MFMA(aP1,bH,c1Z); c1Z=MFMA(aP0,bL,c1Z);
      bH=*(const bf16x8*)(W0iH+(size_t)cN*32+o); bL=*(const bf16x8*)(W0iL+(size_t)cN*32+o);
      c1Ni=MFMA(aP0,bH,c1Ni); c1Ni=MFMA(aP1,bH,c1Ni); c1Ni=MFMA(aP0,bL,c1Ni);
#pragma unroll
      for (int r=0;r<4;++r){
        const int m = quad*4+r;
        float rr = sigm_(c1R[r] + b1R);
        float z  = sigm_(c1Z[r] + b1Z);
        float nn = tanh_(c1Ni[r] + b1Ni + rr*(c1Nh[r] + b1Nh));
        float hold = (float)h1H[m*136+jc] + (float)h1L[m*136+jc];
        float hnew = fin_((1.f-z)*nn + z*hold);
        bf16 hi=(bf16)hnew;
        h1H[m*136+jc]=hi; h1L[m*136+jc]=(bf16)(hnew-(float)hi);
      }
    }
    __syncthreads();                       // B1: h1(t) visible
    // ---- P2: gi2 (h1(t), K=128; W1i-hi from LDS, lo from L2) + gates2 + write h2(t) ----
    {
      f32x4 c2Ni = Z4;
#pragma unroll
      for (int ks=0;ks<4;++ks){
        const int o = ks*32 + quad*8;
        bf16x8 aH = *(const bf16x8*)&h1H[lh*136 + o];
        bf16x8 aL = *(const bf16x8*)&h1L[lh*136 + o];
        bf16x8 bH,bL;
        bH=*(const bf16x8*)&w1iLds[cR*136+o]; bL=*(const bf16x8*)(W1iL+(size_t)cR*128+o);
        c2R=MFMA(aH,bH,c2R); c2R=MFMA(aL,bH,c2R); c2R=MFMA(aH,bL,c2R);
        bH=*(const bf16x8*)&w1iLds[cZ*136+o]; bL=*(const bf16x8*)(W1iL+(size_t)cZ*128+o);
        c2Z=MFMA(aH,bH,c2Z); c2Z=MFMA(aL,bH,c2Z); c2Z=MFMA(aH,bL,c2Z);
        bH=*(const bf16x8*)&w1iLds[cN*136+o]; bL=*(const bf16x8*)(W1iL+(size_t)cN*128+o);
        c2Ni=MFMA(aH,bH,c2Ni); c2Ni=MFMA(aL,bH,c2Ni); c2Ni=MFMA(aH,bL,c2Ni);
      }
#pragma unroll
      for (int r=0;r<4;++r){
        const int m = quad*4+r;
        float rr = sigm_(c2R[r] + b2R);
        float z  = sigm_(c2Z[r] + b2Z);
        float nn = tanh_(c2Ni[r] + b2Ni + rr*(c2Nh[r] + b2Nh));
        float hold = (float)h2H[m*136+jc] + (float)h2L[m*136+jc];
        float hnew = fin_((1.f-z)*nn + z*hold);
        bf16 hi=(bf16)hnew;
        h2H[m*136+jc]=hi; h2L[m*136+jc]=(bf16)(hnew-(float)hi);
      }
    }
    __syncthreads();                       // B2: h2(t) visible
    // ---- P3: out-proj (waves 0,1) + gh precompute for t+1 ----
    if (wave<2){
      f32x4 po=Z4;
#pragma unroll
      for (int ks=0;ks<4;++ks){
        const int o = ks*32 + quad*8;
        bf16x8 oH = *(const bf16x8*)&h2H[lh*136 + o];
        bf16x8 oL = *(const bf16x8*)&h2L[lh*136 + o];
        bf16x8 bH = *(const bf16x8*)(WoH + (size_t)(wave*16+lh)*128 + o);
        bf16x8 bL = *(const bf16x8*)(WoL + (size_t)(wave*16+lh)*128 + o);
        po=MFMA(oH,bH,po); po=MFMA(oL,bH,po); po=MFMA(oH,bL,po);
      }
#pragma unroll
      for (int r=0;r<4;++r){
        const int m = quad*4+r;
        float pv = fin_(po[r]+bo);
        rec[((size_t)(b0+m)*512 + t)*32 + wave*16+lh] = pv;
        bf16 hi=(bf16)pv;
        pH[m*40 + wave*16+lh]=hi; pL[m*40 + wave*16+lh]=(bf16)(pv-(float)hi);
      }
    }
    if (t+1 < 512) ghpre();
    __syncthreads();                       // B3: pred(t) visible
  }
}

// ---------------------------------------------------------------------------
extern "C" void kernel_launch(void* const* d_in, const int* in_sizes, int n_in,
                              void* d_out, int out_size, void* d_ws, size_t ws_size,
                              hipStream_t stream)
{
  const float* x       = (const float*)d_in[0];
  const int*   lengths = (const int*)d_in[1];
  const float* eps     = (const float*)d_in[2];
  const float* eWih0   = (const float*)d_in[3];
  const float* eWhh0   = (const float*)d_in[4];
  const float* ebih0   = (const float*)d_in[5];
  const float* ebhh0   = (const float*)d_in[6];
  const float* eWih12  = (const float*)d_in[7];
  const float* eWhh12  = (const float*)d_in[8];
  const float* ebih12  = (const float*)d_in[9];
  const float* ebhh12  = (const float*)d_in[10];
  const float* dWih0   = (const float*)d_in[11];
  const float* dWhh0   = (const float*)d_in[12];
  const float* dbih0   = (const float*)d_in[13];
  const float* dbhh0   = (const float*)d_in[14];
  const float* dWih1   = (const float*)d_in[15];
  const float* dWhh1   = (const float*)d_in[16];
  const float* dbih1   = (const float*)d_in[17];
  const float* dbhh1   = (const float*)d_in[18];
  const float* Wm      = (const float*)d_in[19];
  const float* bm      = (const float*)d_in[20];
  const float* Wl      = (const float*)d_in[21];
  const float* bl      = (const float*)d_in[22];
  const float* Wz      = (const float*)d_in[23];
  const float* bz      = (const float*)d_in[24];
  const float* Wo      = (const float*)d_in[25];
  const float* bo      = (const float*)d_in[26];

  char* ws = (char*)d_ws;
  bf16* P     = (bf16*)ws;
  bf16* seqA  = (bf16*)(ws + (size_t)(4<<20));
  bf16* seqB  = (bf16*)(ws + (size_t)(68<<20));
  float* hF    = (float*)seqA;
  float* hB    = hF + 256*128;
  float* hInit = hB + 256*128;

  const size_t O_eWih0  = 0;
  const size_t O_eWhh0  = 49152;
  const size_t O_eWih12 = 245760;
  const size_t O_eWhh12 = 1032192;
  const size_t O_dWih0  = 1425408;
  const size_t O_dWhh0  = 1449984;
  const size_t O_dWih1  = 1548288;
  const size_t O_dWhh1  = 1646592;
  const size_t O_Wout   = 1744896;

  float* out   = (float*)d_out;
  float* rec   = out;
  float* omean = out + (size_t)4194304;
  float* ologv = omean + 8192;

  size_t zoff = (size_t)(4<<20);
  size_t zbytes = (size_t)(128<<20);
  if (zoff + zbytes > ws_size) zbytes = (ws_size > zoff)? ws_size - zoff : 0;
  hipMemsetAsync(ws + zoff, 0, zbytes, stream);

  PrepJobs J;
  const float* srcs[9] = {eWih0, eWhh0, eWih12, eWhh12, dWih0, dWhh0, dWih1, dWhh1, Wo};
  const size_t offs[9] = {O_eWih0,O_eWhh0,O_eWih12,O_eWhh12,O_dWih0,O_dWhh0,O_dWih1,O_dWhh1,O_Wout};
  const int    ns[9]   = {24576, 98304, 393216, 196608, 12288, 49152, 49152, 49152, 4096};
  for (int j=0;j<9;++j){ J.src[j]=srcs[j]; J.hi[j]=P+offs[j]; J.lo[j]=P+offs[j]+ns[j]; J.n[j]=ns[j]; }
  prep_w<<<256, 256, 0, stream>>>(J);

  dim3 blk(512);

  enc_rec<32,true><<<32, blk, 0, stream>>>(x, seqA,
      P+O_eWih0, P+O_eWih0+24576, P+O_eWhh0, P+O_eWhh0+98304,
      ebih0, ebhh0, lengths, nullptr, nullptr);
  enc_rec<256,false><<<32, blk, 0, stream>>>(seqA, seqB,
      P+O_eWih12, P+O_eWih12+393216, P+O_eWhh12, P+O_eWhh12+196608,
      ebih12, ebhh12, lengths, nullptr, nullptr);
  enc_rec<256,false><<<32, blk, 0, stream>>>(seqB, nullptr,
      P+O_eWih12+196608, P+O_eWih12+393216+196608,
      P+O_eWhh12+98304,  P+O_eWhh12+196608+98304,
      ebih12+768, ebhh12+768, lengths, hF, hB);
  latent_k<<<256, 64, 0, stream>>>(hF, hB, eps, Wm, bm, Wl, bl, Wz, bz,
                                   omean, ologv, hInit);
  dec_rec<<<16, blk, 0, stream>>>(hInit,
      P+O_dWih0, P+O_dWih0+12288, P+O_dWhh0, P+O_dWhh0+49152,
      P+O_dWih1, P+O_dWih1+49152, P+O_dWhh1, P+O_dWhh1+49152,
      P+O_Wout,  P+O_Wout+4096,
      dbih0, dbhh0, dbih1, dbhh1, bo, rec);
}